// Round 6
// baseline (201.832 us; speedup 1.0000x reference)
//
#include <hip/hip_runtime.h>

#define NCOLS 65536
#define NROWS 256
#define HID 64

// g3(p,s) lookup table: p in [-0.5,0.5] x s in [0,1)
#define TP 64             // p grid points
#define TS 64             // s grid points
#define TST 68            // padded LDS row stride in words (68%32=4, float4-aligned)
#define PSCALE 63.0f      // TP-1
#define SSCALE 63.0f      // TS-1

#define THREADS 256       // 4 waves
#define WAVES 4
#define CPB 1024          // 4 cols/lane * 64 lanes * 4 waves
#define RPB 32            // grid = 64 x 8 = 512 blocks = exactly 2/CU
#define DEPTH 4           // per-wave LDS ring slots (3 rows staged ahead)

typedef const __attribute__((address_space(1))) void* as1p;
typedef __attribute__((address_space(3))) void* as3p;

// direct-to-LDS DMA, 16 B/lane: per-lane global addr, wave-uniform LDS base.
// Data never touches VGPRs -> the RA can't sink/serialize it (rounds 2-5 failure).
#define GSTAGE(gsrc, ldst) \
    __builtin_amdgcn_global_load_lds((as1p)(const void*)(gsrc), (as3p)(void*)(ldst), 16, 0, 0)

// counted vmcnt wait (stores count too on gfx9 -- included in the constants below),
// + sched_barrier so nothing is machine-scheduled above the wait (rule 18).
#define VMWAIT(N) do { asm volatile("s_waitcnt vmcnt(" #N ")" ::: "memory"); \
                       __builtin_amdgcn_sched_barrier(0); } while (0)

// ---- builder: exact MLP evaluated on the (p,s) grid with ib = i_b[0] ----
__global__ void soen_build(const float* __restrict__ i_b, const float* __restrict__ w1,
                           const float* __restrict__ b1, const float* __restrict__ w2,
                           const float* __restrict__ b2, float* __restrict__ tabg)
{
    const int e = blockIdx.x * blockDim.x + threadIdx.x;   // grid sized exactly TP*TS
    const int ip = e / TS;
    const int is = e - ip * TS;
    const float p  = -0.5f + (float)ip * (1.0f / PSCALE);
    const float sv = (float)is * (1.0f / SSCALE);
    const float ib = i_b[0];
    float acc = b2[0];
    #pragma unroll 4
    for (int j = 0; j < HID; j++) {
        const float a = fmaf(p, w1[j], fmaf(sv, w1[HID + j], fmaf(ib, w1[2 * HID + j], b1[j])));
        const float ex = __builtin_amdgcn_exp2f(2.8853900817779268f * a);
        const float th = 1.0f - 2.0f * __builtin_amdgcn_rcpf(1.0f + ex);
        acc = fmaf(w2[j], th, acc);
    }
    tabg[e] = acc;
}

__device__ __forceinline__ float soen_g3_exact(float p, float svv, float ibl,
        const float* __restrict__ w1, const float* __restrict__ b1,
        const float* __restrict__ w2, const float* __restrict__ b2)
{
    float acc = b2[0];
    for (int j = 0; j < HID; j++) {
        const float a = fmaf(p, w1[j], fmaf(svv, w1[HID + j], fmaf(ibl, w1[2 * HID + j], b1[j])));
        const float ex = __builtin_amdgcn_exp2f(2.8853900817779268f * a);
        const float th = 1.0f - 2.0f * __builtin_amdgcn_rcpf(1.0f + ex);
        acc = fmaf(w2[j], th, acc);
    }
    return acc;
}

// branchless per-element: g0..g2 + bilinear-table g3, select by idx. NO control flow.
__device__ __forceinline__ float soen_elem(float phv, float svv, int idx,
                                           const float* __restrict__ tab)
{
    const float p  = phv - rintf(phv);                     // half-to-even, matches jnp.round
    const float p2 = p * p;
    const float g0 = fmaxf(fabsf(p) - svv, 0.f);
    // tanh(p), |p|<=0.5, odd series err<5e-4
    const float tp = p * fmaf(p2, fmaf(p2, 0.13333333f, -0.33333333f), 1.f);
    const float g1 = fmaf(-tp, svv, tp);
    const float g2 = __builtin_amdgcn_exp2f(-14.426950408889634f * p2) - svv;
    const float u  = fmaf(p, PSCALE, 0.5f * PSCALE);       // [0,63]
    const float vv = svv * SSCALE;                         // [0,63)
    int iu = (int)u;  iu = iu > TP - 2 ? TP - 2 : iu;
    int iv = (int)vv; iv = iv > TS - 2 ? TS - 2 : iv;
    const float du = u - (float)iu;
    const float dv = vv - (float)iv;
    const float* bp = tab + iu * TST + iv;
    const float t00 = bp[0],   t01 = bp[1];
    const float t10 = bp[TST], t11 = bp[TST + 1];
    const float a0 = fmaf(dv, t01 - t00, t00);
    const float a1 = fmaf(dv, t11 - t10, t10);
    const float g3 = fmaf(du, a1 - a0, a0);
    return (idx == 0) ? g0 : (idx == 1) ? g1 : (idx == 2) ? g2 : g3;
}

__global__ __launch_bounds__(THREADS) void soen_main(
    const float* __restrict__ phi, const float* __restrict__ s,
    const float* __restrict__ i_b, const float* __restrict__ w1,
    const float* __restrict__ b1, const float* __restrict__ w2,
    const float* __restrict__ b2, const int* __restrict__ func_idx,
    const float* __restrict__ tabg, float* __restrict__ out)
{
    __shared__ float tab[TP * TST];                        // 17408 B
    __shared__ float ring[WAVES][DEPTH][2][256];           // 32768 B: per-wave 4-slot ring

    const int t = threadIdx.x;
    const int w = t >> 6;
    const int lane = t & 63;

    for (int i = t; i < TP * TS / 4; i += THREADS) {       // stage table (4 iters)
        const float4 v = ((const float4*)tabg)[i];
        const int e = i << 2;
        *(float4*)&tab[(e >> 6) * TST + (e & 63)] = v;     // aligned: TST%4==0
    }

    const int col = blockIdx.x * CPB + (t << 2);           // = w*256 + lane*4
    const int rowbase = blockIdx.y * RPB;
    const int4   fidx = *(const int4*)(func_idx + col);
    const float4 ib4  = *(const float4*)(i_b + col);
    const float  ib0  = i_b[0];

    const size_t base = (size_t)rowbase * NCOLS + col;
    const float* gp = phi + base;                          // this lane's 16B row chunk
    const float* gs = s + base;
    float4*      po = (float4*)(out + base);
    const size_t STRV = NCOLS / 4;

    __syncthreads();                                       // drains vmcnt to 0 before pipeline

    // wave-uniform fallback check; consuming fidx/ib4/ib0 here forces those loads to
    // retire before the pipeline starts (keeps the vmcnt bookkeeping exact).
    const bool slow = __any((fidx.x == 3 && ib4.x != ib0) || (fidx.y == 3 && ib4.y != ib0) ||
                            (fidx.z == 3 && ib4.z != ib0) || (fidx.w == 3 && ib4.w != ib0));

    if (__builtin_expect(!slow, 1)) {
        // per-wave LDS-DMA pipeline, no barriers, no VGPR staging.
        auto stage = [&](int r) {
            const int slot = r & (DEPTH - 1);
            GSTAGE(gp + (size_t)r * NCOLS, &ring[w][slot][0][0]);   // lane i -> [i*4..i*4+3]
            GSTAGE(gs + (size_t)r * NCOLS, &ring[w][slot][1][0]);
        };
        auto body = [&](int r) {
            const int slot = r & (DEPTH - 1);
            const float4 P = *(const float4*)&ring[w][slot][0][lane << 2];
            const float4 S = *(const float4*)&ring[w][slot][1][lane << 2];
            float4 o;
            o.x = soen_elem(P.x, S.x, fidx.x, tab);
            o.y = soen_elem(P.y, S.y, fidx.y, tab);
            o.z = soen_elem(P.z, S.z, fidx.z, tab);
            o.w = soen_elem(P.w, S.w, fidx.w, tab);
            po[(size_t)r * STRV] = o;
        };
        // vm-op order per wave: P0 P1 P2 | P3 W b0(ST0) | P4 W b1(ST1) | ...
        // wait constants = #vm-ops newer than row r's stage pair (stores count on gfx9).
        stage(0); stage(1); stage(2);
        stage(3); VMWAIT(6); body(0);
        stage(4); VMWAIT(7); body(1);
        stage(5); VMWAIT(8); body(2);
        #pragma unroll 2
        for (int r = 3; r <= RPB - 4; r++) {               // r = 3..28, steady state
            stage(r + 3);
            VMWAIT(9);
            body(r);
        }
        VMWAIT(7); body(RPB - 3);
        VMWAIT(5); body(RPB - 2);
        VMWAIT(3); body(RPB - 1);
    } else {
        // SLOW PATH (cold, never taken when i_b is uniform): exact per-element fallback
        for (int r = 0; r < RPB; r++) {
            const float4 P = *(const float4*)(gp + (size_t)r * NCOLS);
            const float4 S = *(const float4*)(gs + (size_t)r * NCOLS);
            float4 o;
            o.x = soen_elem(P.x, S.x, fidx.x, tab);
            o.y = soen_elem(P.y, S.y, fidx.y, tab);
            o.z = soen_elem(P.z, S.z, fidx.z, tab);
            o.w = soen_elem(P.w, S.w, fidx.w, tab);
            if (fidx.x == 3 && ib4.x != ib0) o.x = soen_g3_exact(P.x - rintf(P.x), S.x, ib4.x, w1, b1, w2, b2);
            if (fidx.y == 3 && ib4.y != ib0) o.y = soen_g3_exact(P.y - rintf(P.y), S.y, ib4.y, w1, b1, w2, b2);
            if (fidx.z == 3 && ib4.z != ib0) o.z = soen_g3_exact(P.z - rintf(P.z), S.z, ib4.z, w1, b1, w2, b2);
            if (fidx.w == 3 && ib4.w != ib0) o.w = soen_g3_exact(P.w - rintf(P.w), S.w, ib4.w, w1, b1, w2, b2);
            po[(size_t)r * STRV] = o;
        }
    }
}

extern "C" void kernel_launch(void* const* d_in, const int* in_sizes, int n_in,
                              void* d_out, int out_size, void* d_ws, size_t ws_size,
                              hipStream_t stream)
{
    const float* phi      = (const float*)d_in[0];
    const float* s        = (const float*)d_in[1];
    const float* i_b      = (const float*)d_in[2];
    const float* w1       = (const float*)d_in[3];
    const float* b1       = (const float*)d_in[4];
    const float* w2       = (const float*)d_in[5];
    const float* b2       = (const float*)d_in[6];
    const int*   func_idx = (const int*)d_in[7];
    float* outp = (float*)d_out;
    float* tabg = (float*)d_ws;                            // needs TP*TS*4 = 16 KB of workspace

    soen_build<<<dim3(TP * TS / THREADS), dim3(THREADS), 0, stream>>>(i_b, w1, b1, w2, b2, tabg);

    dim3 grid(NCOLS / CPB, NROWS / RPB);                   // 64 x 8 = 512 blocks
    soen_main<<<grid, dim3(THREADS), 0, stream>>>(phi, s, i_b, w1, b1, w2, b2, func_idx,
                                                  tabg, outp);
}